// Round 7
// baseline (1895.845 us; speedup 1.0000x reference)
//
#include <hip/hip_runtime.h>
#include <math.h>

#define NLEV 16
#define TSIZE 524288
#define TMASK (TSIZE - 1)
#define P1 2654435761u
#define P2 805459861u
#define NB 32768   // 15-bit Morton buckets (res-32 cubes)

struct Params {
    int res[NLEV];
    unsigned ncell[5];   // (res+1)^3 for dense levels
    unsigned doff[5];    // float4 offsets into dense_pairs
};

typedef short short8 __attribute__((ext_vector_type(8)));
typedef float f32x4 __attribute__((ext_vector_type(4)));

union U4S8 { uint4 u; short8 s; };
__device__ __forceinline__ short8 as_s8(uint4 u) { U4S8 x; x.u = u; return x.s; }

__device__ __forceinline__ float clamp01f(float v) {
    return fminf(fmaxf(v, 0.0f), 1.0f);
}
__device__ __forceinline__ unsigned f2bf(float f) {
    union { float f; unsigned u; } c; c.f = f;
    return (c.u + 0x7FFFu + ((c.u >> 16) & 1u)) >> 16;
}
__device__ __forceinline__ float bflo(unsigned u) {
    union { unsigned u; float f; } c; c.u = u << 16; return c.f;
}
__device__ __forceinline__ float bfhi(unsigned u) {
    union { unsigned u; float f; } c; c.u = u & 0xFFFF0000u; return c.f;
}
__device__ __forceinline__ unsigned spread5(unsigned v) {
    return (v & 1u) | ((v & 2u) << 2) | ((v & 4u) << 4) |
           ((v & 8u) << 6) | ((v & 16u) << 8);
}
__device__ __forceinline__ unsigned morton_key(float x0, float y0, float z0) {
    unsigned kx = min(31u, (unsigned)(x0 * 32.0f));
    unsigned ky = min(31u, (unsigned)(y0 * 32.0f));
    unsigned kz = min(31u, (unsigned)(z0 * 32.0f));
    return spread5(kx) | (spread5(ky) << 1) | (spread5(kz) << 2);
}

// ---- prep: bf16 hash tables, fp32 dense pair-tables, MFMA weight frags ----
// wf layout (u32): w1hi[1024] | w1lo[1024] | w2hi[512] | w2lo[512]
// w1 frag (j-tile t, lane l, u32 m): k0=8*(l>>4)+2m, j=16t+(l&15); pack(lo=k0,hi=k0+1)
// w2 frag (k-tile s, lane l, u32 m): k0=32s+8*(l>>4)+2m, q=l&15
__global__ __launch_bounds__(256) void prep_kernel(
    const float* __restrict__ tables,
    const float* __restrict__ W1,
    const float* __restrict__ W2,
    unsigned* __restrict__ tbl_bf,       // [11][TSIZE] packed bf16 (levels 5-15)
    float4* __restrict__ dense_pairs,    // overlapping pairs, fp32
    unsigned* __restrict__ wf,
    Params rp)
{
    const unsigned t = blockIdx.x * 256 + threadIdx.x;  // [0, 16*TSIZE)
    const unsigned l = t >> 19, c = t & TMASK;
    const float2* t2 = (const float2*)tables;
    if (l >= 5) {
        const float2 v = t2[(size_t)l * TSIZE + c];
        tbl_bf[(size_t)(l - 5) * TSIZE + c] = f2bf(v.x) | (f2bf(v.y) << 16);
    } else if (c < rp.ncell[l]) {
        const float2 a = t2[(size_t)l * TSIZE + c];
        const float2 b = t2[(size_t)l * TSIZE + c + 1];
        dense_pairs[rp.doff[l] + c] = make_float4(a.x, a.y, b.x, b.y);
    }
    if (blockIdx.x == 0) {
        for (int idx = threadIdx.x; idx < 1024; idx += 256) {
            const int jt = idx >> 8, rem = idx & 255, ln = rem >> 2, m = rem & 3;
            const int k0 = 8 * (ln >> 4) + 2 * m, j = 16 * jt + (ln & 15);
            const float f0 = W1[k0 * 64 + j], f1 = W1[(k0 + 1) * 64 + j];
            const unsigned h0 = f2bf(f0), h1 = f2bf(f1);
            wf[idx] = h0 | (h1 << 16);
            wf[1024 + idx] = f2bf(f0 - bflo(h0)) | (f2bf(f1 - bflo(h1)) << 16);
        }
        for (int idx = threadIdx.x; idx < 512; idx += 256) {
            const int s = idx >> 8, rem = idx & 255, ln = rem >> 2, m = rem & 3;
            const int k0 = 32 * s + 8 * (ln >> 4) + 2 * m, q = ln & 15;
            const float f0 = W2[k0 * 16 + q], f1 = W2[(k0 + 1) * 16 + q];
            const unsigned h0 = f2bf(f0), h1 = f2bf(f1);
            wf[2048 + idx] = h0 | (h1 << 16);
            wf[2560 + idx] = f2bf(f0 - bflo(h0)) | (f2bf(f1 - bflo(h1)) << 16);
        }
    }
}

// ---------------- counting sort by Morton key ------------------------------
__global__ __launch_bounds__(256) void zero_kernel(unsigned* __restrict__ hist) {
    hist[blockIdx.x * 256 + threadIdx.x] = 0u;
}

__global__ __launch_bounds__(256) void hist_kernel(
    const float* __restrict__ xyzs, unsigned* __restrict__ hist)
{
    const int gid = blockIdx.x * 256 + threadIdx.x;
    const float x0 = clamp01f((xyzs[3 * gid + 0] + 1.0f) * 0.5f);
    const float y0 = clamp01f((xyzs[3 * gid + 1] + 1.0f) * 0.5f);
    const float z0 = clamp01f((xyzs[3 * gid + 2] + 1.0f) * 0.5f);
    atomicAdd(&hist[morton_key(x0, y0, z0)], 1u);
}

__global__ __launch_bounds__(1024) void scan_kernel(
    const unsigned* __restrict__ hist, unsigned* __restrict__ work)
{
    __shared__ unsigned part[1024];
    const int tid = threadIdx.x;
    unsigned loc[32], s = 0;
#pragma unroll
    for (int i = 0; i < 32; ++i) { loc[i] = hist[tid * 32 + i]; s += loc[i]; }
    part[tid] = s; __syncthreads();
    for (int st = 1; st < 1024; st <<= 1) {
        unsigned t = (tid >= st) ? part[tid - st] : 0u;
        __syncthreads();
        part[tid] += t;
        __syncthreads();
    }
    unsigned base = (tid == 0) ? 0u : part[tid - 1];
#pragma unroll
    for (int i = 0; i < 32; ++i) { work[tid * 32 + i] = base; base += loc[i]; }
}

__global__ __launch_bounds__(256) void scatter_kernel(
    const float* __restrict__ xyzs, unsigned* __restrict__ work,
    float4* __restrict__ sorted, unsigned* __restrict__ perm)
{
    const int gid = blockIdx.x * 256 + threadIdx.x;
    const float x0 = clamp01f((xyzs[3 * gid + 0] + 1.0f) * 0.5f);
    const float y0 = clamp01f((xyzs[3 * gid + 1] + 1.0f) * 0.5f);
    const float z0 = clamp01f((xyzs[3 * gid + 2] + 1.0f) * 0.5f);
    const unsigned pos = atomicAdd(&work[morton_key(x0, y0, z0)], 1u);
    sorted[pos] = make_float4(x0, y0, z0, 0.0f);
    perm[pos] = (unsigned)gid;
}

// ---------------- dense levels 0..4 on sorted points (fp32 pair-gathers) ---
__global__ __launch_bounds__(256) void enc_dense_sorted(
    const float4* __restrict__ sorted,
    const float4* __restrict__ dense_pairs,
    unsigned* __restrict__ enc_ws,
    Params rp, int N)
{
    const int gid = blockIdx.x * 256 + threadIdx.x;
    const float4 p = sorted[gid];
    const float x0 = p.x, y0 = p.y, z0 = p.z;

#pragma unroll
    for (int l = 0; l < 5; ++l) {
        const int res = rp.res[l];
        const float rf = (float)res;
        const float px = x0 * rf, py = y0 * rf, pz = z0 * rf;
        const float fx = floorf(px), fy = floorf(py), fz = floorf(pz);
        const float rx = px - fx, ry = py - fy, rz = pz - fz;
        const unsigned ix = (unsigned)fx, iy = (unsigned)fy, iz = (unsigned)fz;

        const unsigned s = (unsigned)(res + 1);
        const unsigned ss = s * s;
        const unsigned a = ix + s * iy + ss * iz;
        const float4* dpt = dense_pairs + rp.doff[l];
        const float4 q00 = dpt[a];
        const float4 q01 = dpt[a + ss];
        const float4 q10 = dpt[a + s];
        const float4 q11 = dpt[a + s + ss];

        const float wx0 = 1.0f - rx, wy0 = 1.0f - ry, wz0 = 1.0f - rz;
        float e0, e1;
        e0  = (wx0 * wy0) * wz0 * q00.x;  e1  = (wx0 * wy0) * wz0 * q00.y;
        e0 += (wx0 * wy0) * rz  * q01.x;  e1 += (wx0 * wy0) * rz  * q01.y;
        e0 += (wx0 * ry ) * wz0 * q10.x;  e1 += (wx0 * ry ) * wz0 * q10.y;
        e0 += (wx0 * ry ) * rz  * q11.x;  e1 += (wx0 * ry ) * rz  * q11.y;
        e0 += (rx  * wy0) * wz0 * q00.z;  e1 += (rx  * wy0) * wz0 * q00.w;
        e0 += (rx  * wy0) * rz  * q01.z;  e1 += (rx  * wy0) * rz  * q01.w;
        e0 += (rx  * ry ) * wz0 * q10.z;  e1 += (rx  * ry ) * wz0 * q10.w;
        e0 += (rx  * ry ) * rz  * q11.z;  e1 += (rx  * ry ) * rz  * q11.w;

        __builtin_nontemporal_store(f2bf(e0) | (f2bf(e1) << 16),
                                    enc_ws + (size_t)l * N + gid);
    }
}

// ---------------- one hashed level, 4 pts/thread, optional NT gathers ------
template<int LEVEL, int NT>
__global__ __launch_bounds__(256) void enc_hash_sorted(
    const float4* __restrict__ sorted,
    const unsigned* __restrict__ tbl_bf,
    unsigned* __restrict__ enc_ws,
    int res, int N)
{
    const int g0 = blockIdx.x * 1024 + threadIdx.x;
    const unsigned* tl = tbl_bf + (size_t)(LEVEL - 5) * TSIZE;
    const float rf = (float)res;

    unsigned v[4][8];
    float rx[4], ry[4], rz[4];

#pragma unroll
    for (int p = 0; p < 4; ++p) {
        const float4 pt = sorted[g0 + 256 * p];
        const float px = pt.x * rf, py = pt.y * rf, pz = pt.z * rf;
        const float fx = floorf(px), fy = floorf(py), fz = floorf(pz);
        rx[p] = px - fx; ry[p] = py - fy; rz[p] = pz - fz;
        const unsigned ix = (unsigned)fx, iy = (unsigned)fy, iz = (unsigned)fz;
        const unsigned ax0 = ix,        ax1 = ix + 1u;
        const unsigned by0 = iy * P1,   by1 = (iy + 1u) * P1;
        const unsigned cz0 = iz * P2,   cz1 = (iz + 1u) * P2;
        unsigned idx[8];
        idx[0] = (ax0 ^ by0 ^ cz0) & TMASK;
        idx[1] = (ax0 ^ by0 ^ cz1) & TMASK;
        idx[2] = (ax0 ^ by1 ^ cz0) & TMASK;
        idx[3] = (ax0 ^ by1 ^ cz1) & TMASK;
        idx[4] = (ax1 ^ by0 ^ cz0) & TMASK;
        idx[5] = (ax1 ^ by0 ^ cz1) & TMASK;
        idx[6] = (ax1 ^ by1 ^ cz0) & TMASK;
        idx[7] = (ax1 ^ by1 ^ cz1) & TMASK;
#pragma unroll
        for (int c = 0; c < 8; ++c)
            v[p][c] = NT ? __builtin_nontemporal_load(tl + idx[c]) : tl[idx[c]];
    }

#pragma unroll
    for (int p = 0; p < 4; ++p) {
        const float wx0 = 1.0f - rx[p], wy0 = 1.0f - ry[p], wz0 = 1.0f - rz[p];
        float e0 = 0.0f, e1 = 0.0f;
#pragma unroll
        for (int c = 0; c < 8; ++c) {
            const float wx = (c & 4) ? rx[p] : wx0;
            const float wy = (c & 2) ? ry[p] : wy0;
            const float wz = (c & 1) ? rz[p] : wz0;
            const float w = (wx * wy) * wz;
            e0 += w * bflo(v[p][c]);
            e1 += w * bfhi(v[p][c]);
        }
        __builtin_nontemporal_store(f2bf(e0) | (f2bf(e1) << 16),
                                    enc_ws + (size_t)LEVEL * N + g0 + 256 * p);
    }
}

// ---------------- MFMA MLP -------------------------------------------------
// Wave handles 64 points (4 tiles of 16). Layer1: A=enc(16x32 bf16),
// B=W1 frags (hi+lo split); C layout col=lane&15,row=(lane>>4)*4+reg [m89].
// h -> hi/lo bf16 via swizzled per-wave LDS transpose; Layer2 K=64 (2 tiles).
__global__ __launch_bounds__(256) void mlp_mfma_kernel(
    const unsigned* __restrict__ enc_ws,   // [NLEV][N] packed bf16
    const unsigned* __restrict__ perm,
    const unsigned* __restrict__ wf,       // weight fragments
    float* __restrict__ out_sigma,
    float* __restrict__ out_geo,
    int N)
{
    __shared__ short sH[4][4096];   // per-wave: hi[0,2048) lo[2048,4096); 32 KB

    const int tid  = threadIdx.x;
    const int wid  = tid >> 6;
    const int lane = tid & 63;
    const int l15  = lane & 15;
    const int b    = lane >> 4;
    const int wbase = blockIdx.x * 256 + wid * 64;
    short* sHw = &sH[wid][0];

    // weight fragments -> registers (per-lane uint4, coalesced)
    uint4 w1h[4], w1l[4], w2h[2], w2l[2];
#pragma unroll
    for (int t = 0; t < 4; ++t) {
        w1h[t] = *(const uint4*)&wf[t * 256 + lane * 4];
        w1l[t] = *(const uint4*)&wf[1024 + t * 256 + lane * 4];
    }
#pragma unroll
    for (int s = 0; s < 2; ++s) {
        w2h[s] = *(const uint4*)&wf[2048 + s * 256 + lane * 4];
        w2l[s] = *(const uint4*)&wf[2560 + s * 256 + lane * 4];
    }

    // A fragments: lane holds point (wbase+16*pt+l15), k=8b..8b+7
    // = levels 4b..4b+3 (u32 pair each)
    uint4 af[4];
#pragma unroll
    for (int pt = 0; pt < 4; ++pt) {
        const int p = wbase + 16 * pt + l15;
        af[pt].x = __builtin_nontemporal_load(enc_ws + (size_t)(4 * b + 0) * N + p);
        af[pt].y = __builtin_nontemporal_load(enc_ws + (size_t)(4 * b + 1) * N + p);
        af[pt].z = __builtin_nontemporal_load(enc_ws + (size_t)(4 * b + 2) * N + p);
        af[pt].w = __builtin_nontemporal_load(enc_ws + (size_t)(4 * b + 3) * N + p);
    }

#pragma unroll
    for (int pt = 0; pt < 4; ++pt) {
        const short8 a = as_s8(af[pt]);
        f32x4 c[4];
#pragma unroll
        for (int jt = 0; jt < 4; ++jt) {
            f32x4 z = {0.f, 0.f, 0.f, 0.f};
            z = __builtin_amdgcn_mfma_f32_16x16x32_bf16(a, as_s8(w1l[jt]), z, 0, 0, 0);
            z = __builtin_amdgcn_mfma_f32_16x16x32_bf16(a, as_s8(w1h[jt]), z, 0, 0, 0);
            c[jt] = z;
        }
        // relu + hi/lo bf16 -> swizzled LDS (row=point-in-tile, 64 bf16/row)
#pragma unroll
        for (int jt = 0; jt < 4; ++jt) {
#pragma unroll
            for (int r = 0; r < 4; ++r) {
                const int rowpt = 4 * b + r;
                const int chunk = 2 * jt + (l15 >> 3);
                const int swz = chunk ^ (rowpt & 7);
                const int off = rowpt * 64 + swz * 8 + (l15 & 7);
                const float h = fmaxf(c[jt][r], 0.0f);
                const unsigned hh = f2bf(h);
                sHw[off] = (short)hh;
                sHw[2048 + off] = (short)f2bf(h - bflo(hh));
            }
        }
        // layer 2: A row=l15 (point), k=8b..8b+7 of h
        f32x4 c2 = {0.f, 0.f, 0.f, 0.f};
#pragma unroll
        for (int s = 0; s < 2; ++s) {
            const int off = (l15 * 8 + ((4 * s + b) ^ (l15 & 7))) * 8;
            const short8 ahi = as_s8(*(const uint4*)&sHw[off]);
            const short8 alo = as_s8(*(const uint4*)&sHw[2048 + off]);
            c2 = __builtin_amdgcn_mfma_f32_16x16x32_bf16(ahi, as_s8(w2l[s]), c2, 0, 0, 0);
            c2 = __builtin_amdgcn_mfma_f32_16x16x32_bf16(alo, as_s8(w2h[s]), c2, 0, 0, 0);
            c2 = __builtin_amdgcn_mfma_f32_16x16x32_bf16(ahi, as_s8(w2h[s]), c2, 0, 0, 0);
        }
        // epilogue: lane holds q=l15 for points rowpt=4b+r
#pragma unroll
        for (int r = 0; r < 4; ++r) {
            const unsigned o = perm[wbase + 16 * pt + 4 * b + r];
            const float v = c2[r];
            if (l15 == 0) out_sigma[o] = expf(v);
            else          out_geo[(size_t)o * 15 + (l15 - 1)] = v;
        }
    }
}

// ---------------- fallback: proven fused kernel (R1, passed) ---------------
__global__ __launch_bounds__(256) void hashgrid_fused_kernel(
    const float* __restrict__ xyzs,
    const float* __restrict__ tables,
    const float* __restrict__ W1,
    const float* __restrict__ W2,
    float* __restrict__ out_sigma,
    float* __restrict__ out_geo,
    Params rp, int ndense)
{
    __shared__ float sW1t[64 * 32];
    __shared__ float sW2[64 * 16];
    __shared__ float sGeo[256 * 15];

    const int tid = threadIdx.x;
    for (int i = tid; i < 2048; i += 256) {
        int k = i >> 6, j = i & 63;
        sW1t[j * 32 + k] = W1[i];
    }
    for (int i = tid; i < 1024; i += 256) sW2[i] = W2[i];
    __syncthreads();

    const int gid = blockIdx.x * 256 + tid;
    const float x0 = clamp01f((xyzs[3 * gid + 0] + 1.0f) * 0.5f);
    const float y0 = clamp01f((xyzs[3 * gid + 1] + 1.0f) * 0.5f);
    const float z0 = clamp01f((xyzs[3 * gid + 2] + 1.0f) * 0.5f);

    float enc[32];
    const float2* tb = (const float2*)tables;

#pragma unroll
    for (int l = 0; l < NLEV; ++l) {
        const int res = rp.res[l];
        const float rf = (float)res;
        const float px = x0 * rf, py = y0 * rf, pz = z0 * rf;
        const float fx = floorf(px), fy = floorf(py), fz = floorf(pz);
        const float rx = px - fx, ry = py - fy, rz = pz - fz;
        const unsigned ix = (unsigned)fx, iy = (unsigned)fy, iz = (unsigned)fz;

        unsigned idx[8];
        if (l < ndense) {
            const unsigned s = (unsigned)(res + 1);
            const unsigned ss = s * s;
            const unsigned base = ix + s * (iy + s * iz);
            idx[0] = base;          idx[1] = base + ss;
            idx[2] = base + s;      idx[3] = base + s + ss;
            idx[4] = base + 1u;     idx[5] = base + 1u + ss;
            idx[6] = base + 1u + s; idx[7] = base + 1u + s + ss;
        } else {
            const unsigned ax0 = ix,        ax1 = ix + 1u;
            const unsigned by0 = iy * P1,   by1 = (iy + 1u) * P1;
            const unsigned cz0 = iz * P2,   cz1 = (iz + 1u) * P2;
            idx[0] = (ax0 ^ by0 ^ cz0) & TMASK;
            idx[1] = (ax0 ^ by0 ^ cz1) & TMASK;
            idx[2] = (ax0 ^ by1 ^ cz0) & TMASK;
            idx[3] = (ax0 ^ by1 ^ cz1) & TMASK;
            idx[4] = (ax1 ^ by0 ^ cz0) & TMASK;
            idx[5] = (ax1 ^ by0 ^ cz1) & TMASK;
            idx[6] = (ax1 ^ by1 ^ cz0) & TMASK;
            idx[7] = (ax1 ^ by1 ^ cz1) & TMASK;
        }

        const float2* tl = tb + (size_t)l * TSIZE;
        float2 v[8];
#pragma unroll
        for (int c = 0; c < 8; ++c) v[c] = tl[idx[c]];

        const float wx0 = 1.0f - rx, wy0 = 1.0f - ry, wz0 = 1.0f - rz;
        float e0 = 0.0f, e1 = 0.0f;
#pragma unroll
        for (int c = 0; c < 8; ++c) {
            const float wx = (c & 4) ? rx : wx0;
            const float wy = (c & 2) ? ry : wy0;
            const float wz = (c & 1) ? rz : wz0;
            const float w = (wx * wy) * wz;
            e0 += w * v[c].x;
            e1 += w * v[c].y;
        }
        enc[2 * l]     = e0;
        enc[2 * l + 1] = e1;
    }

    float outv[16];
#pragma unroll
    for (int q = 0; q < 16; ++q) outv[q] = 0.0f;

    for (int j = 0; j < 64; ++j) {
        const float4* wrow = (const float4*)&sW1t[j * 32];
        float hj = 0.0f;
#pragma unroll
        for (int kk = 0; kk < 8; ++kk) {
            const float4 wv = wrow[kk];
            hj += enc[4 * kk + 0] * wv.x;
            hj += enc[4 * kk + 1] * wv.y;
            hj += enc[4 * kk + 2] * wv.z;
            hj += enc[4 * kk + 3] * wv.w;
        }
        hj = fmaxf(hj, 0.0f);
        const float4* w2row = (const float4*)&sW2[j * 16];
#pragma unroll
        for (int qq = 0; qq < 4; ++qq) {
            const float4 w2v = w2row[qq];
            outv[4 * qq + 0] += hj * w2v.x;
            outv[4 * qq + 1] += hj * w2v.y;
            outv[4 * qq + 2] += hj * w2v.z;
            outv[4 * qq + 3] += hj * w2v.w;
        }
    }

    out_sigma[gid] = expf(outv[0]);

    const int wave = tid >> 6;
    const int lane = tid & 63;
    float* gs = &sGeo[wave * 960];
#pragma unroll
    for (int q = 1; q < 16; ++q) gs[lane * 15 + (q - 1)] = outv[q];
    __syncthreads();
    const size_t wbase = (size_t)(blockIdx.x * 256 + wave * 64) * 15;
#pragma unroll
    for (int j = 0; j < 15; ++j)
        out_geo[wbase + (size_t)(j * 64 + lane)] = gs[j * 64 + lane];
}

extern "C" void kernel_launch(void* const* d_in, const int* in_sizes, int n_in,
                              void* d_out, int out_size, void* d_ws, size_t ws_size,
                              hipStream_t stream) {
    const float* xyzs   = (const float*)d_in[0];
    const float* tables = (const float*)d_in[1];
    const float* W1     = (const float*)d_in[2];
    const float* W2     = (const float*)d_in[3];
    float* out = (float*)d_out;

    const int N = in_sizes[0] / 3;

    // Replicate reference RES computation bit-for-bit in float64.
    Params rp;
    int ndense = 0;
    const double PLS = exp(log(2048.0 / 16.0) / 15.0);
    bool pattern_ok = true;
    for (int l = 0; l < NLEV; ++l) {
        const double r = ceil(16.0 * pow(PLS, (double)l));
        rp.res[l] = (int)r;
        const long long s = (long long)r + 1;
        const bool dense = (s * s * s <= (long long)TSIZE);
        if (dense) ndense = l + 1;
        if (dense != (l < 5)) pattern_ok = false;
    }
    unsigned doff = 0;
    if (pattern_ok) {
        for (int l = 0; l < 5; ++l) {
            const unsigned s = (unsigned)rp.res[l] + 1;
            rp.ncell[l] = s * s * s;
            rp.doff[l] = doff;
            doff += rp.ncell[l];
        }
    }

    float* out_sigma = out;
    float* out_geo   = out + N;

    const size_t dpB  = (size_t)doff * 16;
    const size_t srtB = (size_t)N * 16;
    const size_t encB = (size_t)NLEV * N * 4;
    const size_t tblB = (size_t)11 * TSIZE * 4;
    const size_t prmB = (size_t)N * 4;
    const size_t hstB = (size_t)NB * 4;
    const size_t wfB  = 3072 * 4;
    const size_t need = dpB + srtB + encB + tblB + prmB + 2 * hstB + wfB;

    if (pattern_ok && ws_size >= need) {
        char* w = (char*)d_ws;
        float4*   dense_pairs = (float4*)w;              w += dpB;
        float4*   sorted      = (float4*)w;              w += srtB;
        unsigned* enc_ws      = (unsigned*)w;            w += encB;
        unsigned* tbl_bf      = (unsigned*)w;            w += tblB;
        unsigned* perm        = (unsigned*)w;            w += prmB;
        unsigned* hist        = (unsigned*)w;            w += hstB;
        unsigned* work        = (unsigned*)w;            w += hstB;
        unsigned* wf          = (unsigned*)w;

        prep_kernel<<<dim3(NLEV * TSIZE / 256), dim3(256), 0, stream>>>(
            tables, W1, W2, tbl_bf, dense_pairs, wf, rp);

        zero_kernel<<<dim3(NB / 256), dim3(256), 0, stream>>>(hist);
        hist_kernel<<<dim3(N / 256), dim3(256), 0, stream>>>(xyzs, hist);
        scan_kernel<<<dim3(1), dim3(1024), 0, stream>>>(hist, work);
        scatter_kernel<<<dim3(N / 256), dim3(256), 0, stream>>>(
            xyzs, work, sorted, perm);

        enc_dense_sorted<<<dim3(N / 256), dim3(256), 0, stream>>>(
            sorted, dense_pairs, enc_ws, rp, N);

        const dim3 g4(N / 1024), blk(256);
        enc_hash_sorted< 5,0><<<g4, blk, 0, stream>>>(sorted, tbl_bf, enc_ws, rp.res[ 5], N);
        enc_hash_sorted< 6,0><<<g4, blk, 0, stream>>>(sorted, tbl_bf, enc_ws, rp.res[ 6], N);
        enc_hash_sorted< 7,0><<<g4, blk, 0, stream>>>(sorted, tbl_bf, enc_ws, rp.res[ 7], N);
        enc_hash_sorted< 8,0><<<g4, blk, 0, stream>>>(sorted, tbl_bf, enc_ws, rp.res[ 8], N);
        enc_hash_sorted< 9,1><<<g4, blk, 0, stream>>>(sorted, tbl_bf, enc_ws, rp.res[ 9], N);
        enc_hash_sorted<10,1><<<g4, blk, 0, stream>>>(sorted, tbl_bf, enc_ws, rp.res[10], N);
        enc_hash_sorted<11,1><<<g4, blk, 0, stream>>>(sorted, tbl_bf, enc_ws, rp.res[11], N);
        enc_hash_sorted<12,1><<<g4, blk, 0, stream>>>(sorted, tbl_bf, enc_ws, rp.res[12], N);
        enc_hash_sorted<13,1><<<g4, blk, 0, stream>>>(sorted, tbl_bf, enc_ws, rp.res[13], N);
        enc_hash_sorted<14,1><<<g4, blk, 0, stream>>>(sorted, tbl_bf, enc_ws, rp.res[14], N);
        enc_hash_sorted<15,1><<<g4, blk, 0, stream>>>(sorted, tbl_bf, enc_ws, rp.res[15], N);

        mlp_mfma_kernel<<<dim3(N / 256), blk, 0, stream>>>(
            enc_ws, perm, wf, out_sigma, out_geo, N);
    } else {
        hashgrid_fused_kernel<<<dim3(N / 256), dim3(256), 0, stream>>>(
            xyzs, tables, W1, W2, out_sigma, out_geo, rp, ndense);
    }
}